// Round 2
// baseline (446.045 us; speedup 1.0000x reference)
//
#include <hip/hip_runtime.h>

typedef __attribute__((ext_vector_type(8))) short short8;
typedef __attribute__((ext_vector_type(4))) float floatx4;

#define MFMA16(a, b, c) __builtin_amdgcn_mfma_f32_16x16x32_bf16(a, b, c, 0, 0, 0)

__device__ __forceinline__ short f2bf(float f) {
    unsigned int u = __float_as_uint(f);
    u = u + 0x7fffu + ((u >> 16) & 1u);
    return (short)(u >> 16);
}

// ---------------------------------------------------------------------------
// Kernel 0: convert Wq/Wk/Wv fp32 [1024][128] -> bf16 transposed [128][1024]
// so the GEMM B-fragment (k-contiguous per lane) is a ds_read_b128.
// ---------------------------------------------------------------------------
__global__ __launch_bounds__(256) void wconv_kernel(const float* __restrict__ Wq,
                                                    const float* __restrict__ Wk,
                                                    const float* __restrict__ Wv,
                                                    short* __restrict__ wt) {
    int idx = blockIdx.x * 256 + threadIdx.x;   // < 3*131072
    int w = idx >> 17;
    int rem = idx & 131071;
    int k = rem >> 7, n = rem & 127;
    const float* W = (w == 0) ? Wq : (w == 1) ? Wk : Wv;
    wt[w * 131072 + n * 1024 + k] = f2bf(W[rem]);
}

// ---------------------------------------------------------------------------
// Kernel 1: C = A[16384x1024](f32) * W (+bias) -> bf16.
// vmode=0: out row-major [16384][128] (q, k)
// vmode=1: out transposed per batch: out[b][d][s] (v, for flash PV B-frags)
// Tile: BM=128, BN=128(full N), BK=64. 256 threads = 4 waves.
// ---------------------------------------------------------------------------
__global__ __launch_bounds__(256, 2) void proj_kernel(const float* __restrict__ A,
                                                      const short* __restrict__ Wt,
                                                      const float* __restrict__ bias,
                                                      short* __restrict__ out,
                                                      int vmode) {
    alignas(16) __shared__ short Al[128][72];   // [m][k], +8 pad
    alignas(16) __shared__ short Wl[128][72];   // [n][k], +8 pad
    const int t = threadIdx.x;
    const int wv = t >> 6, L = t & 63;
    const int q4 = L >> 4, l16 = L & 15;
    const int m0 = blockIdx.x * 128;

    floatx4 acc[2][8];
    for (int mt = 0; mt < 2; mt++)
        for (int nt = 0; nt < 8; nt++) acc[mt][nt] = (floatx4)0.0f;

    for (int k0 = 0; k0 < 1024; k0 += 64) {
        // stage A: 128 rows x 64 cols f32 -> bf16 LDS (1024 chunks of 8)
        for (int j = 0; j < 4; j++) {
            int flat = j * 256 + t;
            int row = flat >> 3, c8 = flat & 7;
            const float* src = A + (size_t)(m0 + row) * 1024 + k0 + c8 * 8;
            float4 f0 = ((const float4*)src)[0];
            float4 f1 = ((const float4*)src)[1];
            short8 v;
            v[0] = f2bf(f0.x); v[1] = f2bf(f0.y); v[2] = f2bf(f0.z); v[3] = f2bf(f0.w);
            v[4] = f2bf(f1.x); v[5] = f2bf(f1.y); v[6] = f2bf(f1.z); v[7] = f2bf(f1.w);
            *(short8*)&Al[row][c8 * 8] = v;
        }
        // stage Wt: 128 rows x 64 cols bf16 straight copy
        for (int j = 0; j < 4; j++) {
            int flat = j * 256 + t;
            int row = flat >> 3, c8 = flat & 7;
            *(short8*)&Wl[row][c8 * 8] = *(const short8*)(Wt + row * 1024 + k0 + c8 * 8);
        }
        __syncthreads();
        for (int ks = 0; ks < 2; ks++) {
            short8 a0 = *(short8*)&Al[32 * wv + l16][ks * 32 + q4 * 8];
            short8 a1 = *(short8*)&Al[32 * wv + 16 + l16][ks * 32 + q4 * 8];
            for (int nt = 0; nt < 8; nt++) {
                short8 bfr = *(short8*)&Wl[16 * nt + l16][ks * 32 + q4 * 8];
                acc[0][nt] = MFMA16(a0, bfr, acc[0][nt]);
                acc[1][nt] = MFMA16(a1, bfr, acc[1][nt]);
            }
        }
        __syncthreads();
    }

    for (int nt = 0; nt < 8; nt++) {
        float bv = bias[16 * nt + l16];
        for (int mt = 0; mt < 2; mt++) {
            for (int r = 0; r < 4; r++) {
                float val = acc[mt][nt][r] + bv;
                short h = f2bf(val);
                int grow = m0 + 32 * wv + 16 * mt + q4 * 4 + r;   // C/D: row=(lane>>4)*4+r
                int col = 16 * nt + l16;                           //       col=lane&15
                if (vmode == 0) {
                    out[(size_t)grow * 128 + col] = h;
                } else {
                    int bb = grow >> 11, s = grow & 2047;
                    out[(size_t)bb * 262144 + (size_t)col * 2048 + s] = h;
                }
            }
        }
    }
}

// ---------------------------------------------------------------------------
// Kernel 2: flash attention. Block = (q-tile of 64, batch). 4 waves,
// wave w owns q-rows [16w,16w+16). KV-tile = 64. Online softmax in exp2
// domain; P goes C-layout -> LDS -> A-layout (wave-private, no barrier).
// ---------------------------------------------------------------------------
__global__ __launch_bounds__(256, 2) void flash_kernel(const short* __restrict__ qw,
                                                       const short* __restrict__ kw,
                                                       const short* __restrict__ vw,
                                                       float* __restrict__ out) {
    alignas(16) __shared__ short Ql[64][136];   // [q][d]   64 rows x 128 cols
    alignas(16) __shared__ short Kl[64][136];   // [kv][d]  64 rows x 128 cols
    alignas(16) __shared__ short Vl[128][72];   // [d][kv]  128 rows x 64 cols
    alignas(16) __shared__ short Pl[64][72];    // [q][kv]
    const int t = threadIdx.x;
    const int wv = t >> 6, L = t & 63;
    const int q4 = L >> 4, l16 = L & 15;
    const int bq = blockIdx.x, b = blockIdx.y;
    const short* qp = qw + (size_t)b * 262144 + (size_t)bq * 64 * 128;
    const short* kp = kw + (size_t)b * 262144;
    const short* vp = vw + (size_t)b * 262144;

    // stage Q: 64 rows x 128 cols  (row = flat>>4, chunk16 = flat&15)
    for (int j = 0; j < 4; j++) {
        int flat = j * 256 + t;
        int row = flat >> 4, c16 = flat & 15;
        *(short8*)&Ql[row][c16 * 8] = *(const short8*)(qp + row * 128 + c16 * 8);
    }

    floatx4 oacc[8];
    for (int dt = 0; dt < 8; dt++) oacc[dt] = (floatx4)0.0f;
    float m_i[4] = {-1e30f, -1e30f, -1e30f, -1e30f};
    float l_i[4] = {0.f, 0.f, 0.f, 0.f};
    const float SL = (float)(0.08838834764831845 * 1.4426950408889634); // 1/sqrt(128)*log2(e)

    for (int kt = 0; kt < 32; kt++) {
        const int kv0 = kt * 64;
        __syncthreads();   // prev iter's LDS reads done before restaging (iter0: Q visible)
        // stage K-tile: 64 rows x 128 cols
        for (int j = 0; j < 4; j++) {
            int flat = j * 256 + t;
            int row = flat >> 4, c16 = flat & 15;
            *(short8*)&Kl[row][c16 * 8] = *(const short8*)(kp + (size_t)(kv0 + row) * 128 + c16 * 8);
        }
        // stage V-tile (pre-transposed): 128 rows(d) x 64 cols(kv)
        for (int j = 0; j < 4; j++) {
            int flat = j * 256 + t;
            int row = flat >> 3, c8 = flat & 7;
            *(short8*)&Vl[row][c8 * 8] = *(const short8*)(vp + (size_t)row * 2048 + kv0 + c8 * 8);
        }
        __syncthreads();

        // S = Q K^T  (16 q-rows x 64 kv per wave)
        short8 qf[4];
        for (int ks = 0; ks < 4; ks++) qf[ks] = *(short8*)&Ql[16 * wv + l16][ks * 32 + q4 * 8];
        floatx4 sa[4];
        for (int nt = 0; nt < 4; nt++) {
            sa[nt] = (floatx4)0.0f;
            for (int ks = 0; ks < 4; ks++) {
                short8 bfr = *(short8*)&Kl[16 * nt + l16][ks * 32 + q4 * 8];
                sa[nt] = MFMA16(qf[ks], bfr, sa[nt]);
            }
        }

        // online softmax (rows = q4*4+r, cols = 16*nt+l16)
        float p[4][4], mnew[4], alpha[4];
        for (int r = 0; r < 4; r++) {
            float mx = fmaxf(fmaxf(sa[0][r], sa[1][r]), fmaxf(sa[2][r], sa[3][r]));
            mx *= SL;   // SL > 0, max commutes with scale
            for (int off = 8; off >= 1; off >>= 1) mx = fmaxf(mx, __shfl_xor(mx, off, 64));
            mnew[r] = fmaxf(m_i[r], mx);
            alpha[r] = __builtin_amdgcn_exp2f(m_i[r] - mnew[r]);
            float rs = 0.f;
            for (int nt = 0; nt < 4; nt++) {
                float pv = __builtin_amdgcn_exp2f(sa[nt][r] * SL - mnew[r]);
                p[nt][r] = pv;
                rs += pv;
            }
            for (int off = 8; off >= 1; off >>= 1) rs += __shfl_xor(rs, off, 64);
            l_i[r] = l_i[r] * alpha[r] + rs;
            m_i[r] = mnew[r];
        }
        for (int dt = 0; dt < 8; dt++)
            for (int r = 0; r < 4; r++) oacc[dt][r] *= alpha[r];

        // P: C-layout -> LDS (wave-private rows; same-wave RAW is waitcnt-ordered)
        for (int nt = 0; nt < 4; nt++)
            for (int r = 0; r < 4; r++)
                Pl[16 * wv + q4 * 4 + r][16 * nt + l16] = f2bf(p[nt][r]);

        // O += P V
        short8 pf0 = *(short8*)&Pl[16 * wv + l16][q4 * 8];
        short8 pf1 = *(short8*)&Pl[16 * wv + l16][32 + q4 * 8];
        for (int dt = 0; dt < 8; dt++) {
            short8 v0 = *(short8*)&Vl[16 * dt + l16][q4 * 8];
            short8 v1 = *(short8*)&Vl[16 * dt + l16][32 + q4 * 8];
            oacc[dt] = MFMA16(pf0, v0, oacc[dt]);
            oacc[dt] = MFMA16(pf1, v1, oacc[dt]);
        }
    }

    float inv[4];
    for (int r = 0; r < 4; r++) inv[r] = 1.0f / l_i[r];
    for (int dt = 0; dt < 8; dt++) {
        for (int r = 0; r < 4; r++) {
            int qrow = bq * 64 + 16 * wv + q4 * 4 + r;
            out[((size_t)b * 2048 + qrow) * 128 + 16 * dt + l16] = oacc[dt][r] * inv[r];
        }
    }
}

extern "C" void kernel_launch(void* const* d_in, const int* in_sizes, int n_in,
                              void* d_out, int out_size, void* d_ws, size_t ws_size,
                              hipStream_t stream) {
    const float* query = (const float*)d_in[0];
    const float* key   = (const float*)d_in[1];
    const float* value = (const float*)d_in[2];
    const float* Wq    = (const float*)d_in[3];
    const float* bq    = (const float*)d_in[4];
    const float* Wk    = (const float*)d_in[5];
    const float* bk    = (const float*)d_in[6];
    const float* Wv    = (const float*)d_in[7];
    const float* bv    = (const float*)d_in[8];
    float* out = (float*)d_out;

    // ws layout (bf16/short units): Wt[3][128][1024] | q[16384][128] | k[16384][128] | vt[8][128][2048]
    short* wt  = (short*)d_ws;
    short* qws = wt + 3 * 131072;
    short* kws = qws + 16384 * 128;
    short* vws = kws + 16384 * 128;

    wconv_kernel<<<1536, 256, 0, stream>>>(Wq, Wk, Wv, wt);
    proj_kernel<<<128, 256, 0, stream>>>(query, wt,          bq, qws, 0);
    proj_kernel<<<128, 256, 0, stream>>>(key,   wt + 131072, bk, kws, 0);
    proj_kernel<<<128, 256, 0, stream>>>(value, wt + 262144, bv, vws, 1);
    flash_kernel<<<dim3(32, 8), 256, 0, stream>>>(qws, kws, vws, out);
}

// Round 3
// 343.771 us; speedup vs baseline: 1.2975x; 1.2975x over previous
//
#include <hip/hip_runtime.h>

typedef __attribute__((ext_vector_type(8))) short short8;
typedef __attribute__((ext_vector_type(4))) float floatx4;

#define MFMA16(a, b, c) __builtin_amdgcn_mfma_f32_16x16x32_bf16(a, b, c, 0, 0, 0)

__device__ __forceinline__ short f2bf(float f) {
    unsigned int u = __float_as_uint(f);
    u = u + 0x7fffu + ((u >> 16) & 1u);
    return (short)(u >> 16);
}

// ---------------------------------------------------------------------------
// Kernel 0: convert Wq/Wk/Wv fp32 [1024][128] -> bf16 transposed [128][1024]
// ---------------------------------------------------------------------------
__global__ __launch_bounds__(256) void wconv_kernel(const float* __restrict__ Wq,
                                                    const float* __restrict__ Wk,
                                                    const float* __restrict__ Wv,
                                                    short* __restrict__ wt) {
    int idx = blockIdx.x * 256 + threadIdx.x;   // < 3*131072
    int w = idx >> 17;
    int rem = idx & 131071;
    int k = rem >> 7, n = rem & 127;
    const float* W = (w == 0) ? Wq : (w == 1) ? Wk : Wv;
    wt[w * 131072 + n * 1024 + k] = f2bf(W[rem]);
}

// ---------------------------------------------------------------------------
// Kernel 1 (fused q/k/v): C = A[16384x1024](f32) * W (+bias) -> bf16.
// LDS-free: A-frags direct from global fp32 (wave-private rows), W B-frags
// direct 16B loads from bf16 Wt (L1/L2-resident slab). No barriers at all.
// Block = 4 waves, each wave owns a 16-row m-tile; BM=64. Grid (256, 3).
// which = blockIdx.y: 0=q (row-major out), 1=k (row-major), 2=v (transposed).
// ---------------------------------------------------------------------------
__global__ __launch_bounds__(256, 2) void proj_kernel(const float* __restrict__ Q,
                                                      const float* __restrict__ K,
                                                      const float* __restrict__ V,
                                                      const short* __restrict__ wt,
                                                      const float* __restrict__ bq,
                                                      const float* __restrict__ bk,
                                                      const float* __restrict__ bv,
                                                      short* __restrict__ qo,
                                                      short* __restrict__ ko,
                                                      short* __restrict__ vo) {
    const int t = threadIdx.x;
    const int wv = t >> 6, L = t & 63;
    const int q4 = L >> 4, l16 = L & 15;
    const int which = blockIdx.y;
    const float* A = (which == 0) ? Q : (which == 1) ? K : V;
    const short* Wt = wt + which * 131072;
    const float* bias = (which == 0) ? bq : (which == 1) ? bk : bv;

    const int m0 = blockIdx.x * 64 + 16 * wv;          // this wave's m-tile
    const float* arow = A + (size_t)(m0 + l16) * 1024; // A-frag row for this lane

    floatx4 acc[8];
    for (int nt = 0; nt < 8; nt++) acc[nt] = (floatx4)0.0f;

#pragma unroll 2
    for (int k0 = 0; k0 < 1024; k0 += 64) {
        short8 af[2];
        for (int ks = 0; ks < 2; ks++) {
            const float* src = arow + k0 + ks * 32 + q4 * 8;
            float4 f0 = ((const float4*)src)[0];
            float4 f1 = ((const float4*)src)[1];
            short8 v;
            v[0] = f2bf(f0.x); v[1] = f2bf(f0.y); v[2] = f2bf(f0.z); v[3] = f2bf(f0.w);
            v[4] = f2bf(f1.x); v[5] = f2bf(f1.y); v[6] = f2bf(f1.z); v[7] = f2bf(f1.w);
            af[ks] = v;
        }
        for (int nt = 0; nt < 8; nt++) {
            const short* wrow = Wt + (size_t)(16 * nt + l16) * 1024 + k0 + q4 * 8;
            short8 b0 = *(const short8*)wrow;
            short8 b1 = *(const short8*)(wrow + 32);
            acc[nt] = MFMA16(af[0], b0, acc[nt]);
            acc[nt] = MFMA16(af[1], b1, acc[nt]);
        }
    }

    for (int nt = 0; nt < 8; nt++) {
        float bvv = bias[16 * nt + l16];
        for (int r = 0; r < 4; r++) {
            float val = acc[nt][r] + bvv;
            short h = f2bf(val);
            int grow = m0 + q4 * 4 + r;       // C/D: row=(lane>>4)*4+r
            int col = 16 * nt + l16;          //       col=lane&15
            if (which == 0) {
                qo[(size_t)grow * 128 + col] = h;
            } else if (which == 1) {
                ko[(size_t)grow * 128 + col] = h;
            } else {
                int bb = grow >> 11, s = grow & 2047;
                vo[(size_t)bb * 262144 + (size_t)col * 2048 + s] = h;
            }
        }
    }
}

// ---------------------------------------------------------------------------
// Kernel 2: flash attention. Block = (q-tile of 32, batch), 128 threads =
// 2 waves; wave w owns q-rows [16w,16w+16). Grid (64, 8) = 512 blocks ->
// 2 blocks/CU for CU-level overlap. KV-tile = 64. Q-frags direct from global
// (wave-private). Online softmax in exp2 domain; P round-trips wave-private
// LDS (C-layout -> A-layout).
// ---------------------------------------------------------------------------
__global__ __launch_bounds__(128, 2) void flash_kernel(const short* __restrict__ qw,
                                                       const short* __restrict__ kw,
                                                       const short* __restrict__ vw,
                                                       float* __restrict__ out) {
    alignas(16) __shared__ short Kl[64][136];   // [kv][d]  64 x 128 (+8 pad)
    alignas(16) __shared__ short Vl[128][72];   // [d][kv]  128 x 64 (+8 pad)
    alignas(16) __shared__ short Pl[32][72];    // [q][kv]
    const int t = threadIdx.x;
    const int wv = t >> 6, L = t & 63;
    const int q4 = L >> 4, l16 = L & 15;
    const int bq = blockIdx.x, b = blockIdx.y;
    const short* qp = qw + (size_t)b * 262144 + (size_t)bq * 32 * 128;
    const short* kp = kw + (size_t)b * 262144;
    const short* vp = vw + (size_t)b * 262144;

    // Q-frags: wave-private, direct from global (row = 16*wv + l16)
    short8 qf[4];
    for (int ks = 0; ks < 4; ks++)
        qf[ks] = *(const short8*)(qp + (16 * wv + l16) * 128 + ks * 32 + q4 * 8);

    floatx4 oacc[8];
    for (int dt = 0; dt < 8; dt++) oacc[dt] = (floatx4)0.0f;
    float m_i[4] = {-1e30f, -1e30f, -1e30f, -1e30f};
    float l_i[4] = {0.f, 0.f, 0.f, 0.f};
    const float SL = (float)(0.08838834764831845 * 1.4426950408889634); // 1/sqrt(128)*log2(e)

    for (int kt = 0; kt < 32; kt++) {
        const int kv0 = kt * 64;
        __syncthreads();   // prev iter's LDS reads done before restaging
        // stage K-tile: 64 rows x 128 cols, 1024 chunks of 8 / 128 threads
        for (int j = 0; j < 8; j++) {
            int flat = j * 128 + t;
            int row = flat >> 4, c16 = flat & 15;
            *(short8*)&Kl[row][c16 * 8] = *(const short8*)(kp + (size_t)(kv0 + row) * 128 + c16 * 8);
        }
        // stage V-tile (pre-transposed): 128 rows(d) x 64 cols(kv)
        for (int j = 0; j < 8; j++) {
            int flat = j * 128 + t;
            int row = flat >> 3, c8 = flat & 7;
            *(short8*)&Vl[row][c8 * 8] = *(const short8*)(vp + (size_t)row * 2048 + kv0 + c8 * 8);
        }
        __syncthreads();

        // S = Q K^T  (16 q-rows x 64 kv per wave)
        floatx4 sa[4];
        for (int nt = 0; nt < 4; nt++) {
            sa[nt] = (floatx4)0.0f;
            for (int ks = 0; ks < 4; ks++) {
                short8 bfr = *(short8*)&Kl[16 * nt + l16][ks * 32 + q4 * 8];
                sa[nt] = MFMA16(qf[ks], bfr, sa[nt]);
            }
        }

        // online softmax (rows = q4*4+r, cols = 16*nt+l16)
        float p[4][4], mnew[4], alpha[4];
        for (int r = 0; r < 4; r++) {
            float mx = fmaxf(fmaxf(sa[0][r], sa[1][r]), fmaxf(sa[2][r], sa[3][r]));
            mx *= SL;
            for (int off = 8; off >= 1; off >>= 1) mx = fmaxf(mx, __shfl_xor(mx, off, 64));
            mnew[r] = fmaxf(m_i[r], mx);
            alpha[r] = __builtin_amdgcn_exp2f(m_i[r] - mnew[r]);
            float rs = 0.f;
            for (int nt = 0; nt < 4; nt++) {
                float pv = __builtin_amdgcn_exp2f(sa[nt][r] * SL - mnew[r]);
                p[nt][r] = pv;
                rs += pv;
            }
            for (int off = 8; off >= 1; off >>= 1) rs += __shfl_xor(rs, off, 64);
            l_i[r] = l_i[r] * alpha[r] + rs;
            m_i[r] = mnew[r];
        }
        for (int dt = 0; dt < 8; dt++)
            for (int r = 0; r < 4; r++) oacc[dt][r] *= alpha[r];

        // P: C-layout -> LDS (wave-private rows; same-wave RAW waitcnt-ordered)
        for (int nt = 0; nt < 4; nt++)
            for (int r = 0; r < 4; r++)
                Pl[16 * wv + q4 * 4 + r][16 * nt + l16] = f2bf(p[nt][r]);

        // O += P V
        short8 pf0 = *(short8*)&Pl[16 * wv + l16][q4 * 8];
        short8 pf1 = *(short8*)&Pl[16 * wv + l16][32 + q4 * 8];
        for (int dt = 0; dt < 8; dt++) {
            short8 v0 = *(short8*)&Vl[16 * dt + l16][q4 * 8];
            short8 v1 = *(short8*)&Vl[16 * dt + l16][32 + q4 * 8];
            oacc[dt] = MFMA16(pf0, v0, oacc[dt]);
            oacc[dt] = MFMA16(pf1, v1, oacc[dt]);
        }
    }

    float inv[4];
    for (int r = 0; r < 4; r++) inv[r] = 1.0f / l_i[r];
    for (int dt = 0; dt < 8; dt++) {
        for (int r = 0; r < 4; r++) {
            int qrow = bq * 32 + 16 * wv + q4 * 4 + r;
            out[((size_t)b * 2048 + qrow) * 128 + 16 * dt + l16] = oacc[dt][r] * inv[r];
        }
    }
}

extern "C" void kernel_launch(void* const* d_in, const int* in_sizes, int n_in,
                              void* d_out, int out_size, void* d_ws, size_t ws_size,
                              hipStream_t stream) {
    const float* query = (const float*)d_in[0];
    const float* key   = (const float*)d_in[1];
    const float* value = (const float*)d_in[2];
    const float* Wq    = (const float*)d_in[3];
    const float* bq    = (const float*)d_in[4];
    const float* Wk    = (const float*)d_in[5];
    const float* bk    = (const float*)d_in[6];
    const float* Wv    = (const float*)d_in[7];
    const float* bv    = (const float*)d_in[8];
    float* out = (float*)d_out;

    // ws layout (shorts): Wt[3][128][1024] | q[16384][128] | k[16384][128] | vt[8][128][2048]
    short* wt  = (short*)d_ws;
    short* qws = wt + 3 * 131072;
    short* kws = qws + 16384 * 128;
    short* vws = kws + 16384 * 128;

    wconv_kernel<<<1536, 256, 0, stream>>>(Wq, Wk, Wv, wt);
    proj_kernel<<<dim3(256, 3), 256, 0, stream>>>(query, key, value, wt,
                                                  bq, bk, bv, qws, kws, vws);
    flash_kernel<<<dim3(64, 8), 128, 0, stream>>>(qws, kws, vws, out);
}

// Round 4
// 280.320 us; speedup vs baseline: 1.5912x; 1.2264x over previous
//
#include <hip/hip_runtime.h>

typedef __attribute__((ext_vector_type(8))) short short8;
typedef __attribute__((ext_vector_type(4))) float floatx4;

#define MFMA16(a, b, c) __builtin_amdgcn_mfma_f32_16x16x32_bf16(a, b, c, 0, 0, 0)

__device__ __forceinline__ short f2bf(float f) {
    unsigned int u = __float_as_uint(f);
    u = u + 0x7fffu + ((u >> 16) & 1u);
    return (short)(u >> 16);
}

__device__ __forceinline__ void ldst16(const void* g, void* l) {
    __builtin_amdgcn_global_load_lds(
        (const __attribute__((address_space(1))) void*)g,
        (__attribute__((address_space(3))) void*)l, 16, 0, 0);
}

// ---------------------------------------------------------------------------
// Kernel 0: convert Wq/Wk/Wv fp32 [1024][128] -> bf16 transposed [128][1024]
// ---------------------------------------------------------------------------
__global__ __launch_bounds__(256) void wconv_kernel(const float* __restrict__ Wq,
                                                    const float* __restrict__ Wk,
                                                    const float* __restrict__ Wv,
                                                    short* __restrict__ wt) {
    int idx = blockIdx.x * 256 + threadIdx.x;   // < 3*131072
    int w = idx >> 17;
    int rem = idx & 131071;
    int k = rem >> 7, n = rem & 127;
    const float* W = (w == 0) ? Wq : (w == 1) ? Wk : Wv;
    wt[w * 131072 + n * 1024 + k] = f2bf(W[rem]);
}

// ---------------------------------------------------------------------------
// Kernel 1 (fused q/k/v): C = A[16384x1024](f32) * W (+bias) -> bf16.
// m97 structure: global_load_lds(16B) staging into XOR-swizzled LDS tiles
// (swizzle needed because global_load_lds layout is lane-contiguous, no pad).
// BM=64 (1 wave = 16 m-rows), BN=128, BK=64. Grid (256,3) = 768 blocks =
// 3 blocks/CU. A staged fp32, converted to bf16 after ds_read.
// ---------------------------------------------------------------------------
__global__ __launch_bounds__(256, 3) void proj_kernel(const float* __restrict__ Q,
                                                      const float* __restrict__ K,
                                                      const float* __restrict__ V,
                                                      const short* __restrict__ wt,
                                                      const float* __restrict__ bq,
                                                      const float* __restrict__ bk,
                                                      const float* __restrict__ bv,
                                                      short* __restrict__ qo,
                                                      short* __restrict__ ko,
                                                      short* __restrict__ vo) {
    alignas(16) __shared__ float Asl[64 * 64];    // [r][pos], chunk=4 floats, pos=c^(r&15)
    alignas(16) __shared__ short Wsl[128 * 64];   // [r][pos], chunk=8 shorts, pos=c^(r&7)
    const int t = threadIdx.x;
    const int wv = t >> 6, L = t & 63;
    const int q4 = L >> 4, l16 = L & 15;
    const int which = blockIdx.y;
    const float* A = (which == 0) ? Q : (which == 1) ? K : V;
    const short* Wt = wt + which * 131072;
    const float* bias = (which == 0) ? bq : (which == 1) ? bk : bv;
    const int m0 = blockIdx.x * 64;
    const int mw = m0 + 16 * wv;

    floatx4 acc[8];
    for (int nt = 0; nt < 8; nt++) acc[nt] = (floatx4)0.0f;

    for (int k0 = 0; k0 < 1024; k0 += 64) {
        __syncthreads();   // prev iter's ds_reads done before DMA overwrites
        // stage A tile 64x64 f32 (16KB): 4 insts/wave, 1KB each
        for (int j = 0; j < 4; j++) {
            int s = (4 * wv + j) * 64 + L;           // 16B slot id
            int r = s >> 4, p = s & 15, c = p ^ (r & 15);
            ldst16(A + (size_t)(m0 + r) * 1024 + k0 + c * 4,
                   Asl + (4 * wv + j) * 256);
        }
        // stage W tile 128x64 bf16 (16KB)
        for (int j = 0; j < 4; j++) {
            int s = (4 * wv + j) * 64 + L;
            int r = s >> 3, p = s & 7, c = p ^ (r & 7);
            ldst16(Wt + (size_t)r * 1024 + k0 + c * 8,
                   Wsl + (4 * wv + j) * 512);
        }
        __syncthreads();   // drains vmcnt(0): staged data visible

        for (int ks = 0; ks < 2; ks++) {
            int c0 = 8 * ks + 2 * q4;
            const int ar = 16 * wv + l16;
            float4 f0 = *(float4*)&Asl[ar * 64 + (c0 ^ l16) * 4];
            float4 f1 = *(float4*)&Asl[ar * 64 + ((c0 + 1) ^ l16) * 4];
            short8 af;
            af[0] = f2bf(f0.x); af[1] = f2bf(f0.y); af[2] = f2bf(f0.z); af[3] = f2bf(f0.w);
            af[4] = f2bf(f1.x); af[5] = f2bf(f1.y); af[6] = f2bf(f1.z); af[7] = f2bf(f1.w);
            int cw = 4 * ks + q4;
            for (int nt = 0; nt < 8; nt++) {
                int wr = 16 * nt + l16;
                short8 bf = *(short8*)&Wsl[wr * 64 + (cw ^ (l16 & 7)) * 8];
                acc[nt] = MFMA16(af, bf, acc[nt]);
            }
        }
    }

    for (int nt = 0; nt < 8; nt++) {
        float bvv = bias[16 * nt + l16];
        for (int r = 0; r < 4; r++) {
            float val = acc[nt][r] + bvv;
            short h = f2bf(val);
            int grow = mw + q4 * 4 + r;       // C/D: row=(lane>>4)*4+r
            int col = 16 * nt + l16;          //       col=lane&15
            if (which == 0) {
                qo[(size_t)grow * 128 + col] = h;
            } else if (which == 1) {
                ko[(size_t)grow * 128 + col] = h;
            } else {
                int bb = grow >> 11, s = grow & 2047;
                vo[(size_t)bb * 262144 + (size_t)col * 2048 + s] = h;
            }
        }
    }
}

// ---------------------------------------------------------------------------
// Kernel 2: flash attention. Block = (q-tile 32, batch), 256 threads =
// 4 waves = 2 wave-pairs; pair p handles kv range [p*1024, p*1024+1024),
// wave (pair,w) owns q-rows [16w,16w+16). Each pair has private K/V/P LDS
// buffers (80.9KB total -> 2 blocks/CU, 8 waves/CU, serial depth halved).
// LSE-merge of the two pairs through LDS at the end.
// ---------------------------------------------------------------------------
__global__ __launch_bounds__(256, 2) void flash_kernel(const short* __restrict__ qw,
                                                       const short* __restrict__ kw,
                                                       const short* __restrict__ vw,
                                                       float* __restrict__ out) {
    alignas(16) __shared__ short Kl[2][64][136];   // [pair][kv][d]
    alignas(16) __shared__ short Vl[2][128][72];   // [pair][d][kv]
    alignas(16) __shared__ short Pl[2][32][72];    // [pair][q][kv]
    const int t = threadIdx.x;
    const int wv = t >> 6, L = t & 63;
    const int pr = wv >> 1, wq = wv & 1;           // pair, wave-in-pair
    const int pt = t & 127;                        // thread-in-pair
    const int q4 = L >> 4, l16 = L & 15;
    const int bq = blockIdx.x, b = blockIdx.y;
    const short* qp = qw + (size_t)b * 262144 + (size_t)bq * 32 * 128;
    const short* kp = kw + (size_t)b * 262144;
    const short* vp = vw + (size_t)b * 262144;

    // Q-frags: wave-private, direct from global (row = 16*wq + l16)
    short8 qf[4];
    for (int ks = 0; ks < 4; ks++)
        qf[ks] = *(const short8*)(qp + (16 * wq + l16) * 128 + ks * 32 + q4 * 8);

    floatx4 oacc[8];
    for (int dt = 0; dt < 8; dt++) oacc[dt] = (floatx4)0.0f;
    float m_i[4] = {-1e30f, -1e30f, -1e30f, -1e30f};
    float l_i[4] = {0.f, 0.f, 0.f, 0.f};
    const float SL = (float)(0.08838834764831845 * 1.4426950408889634); // 1/sqrt(128)*log2(e)

    for (int kt = 0; kt < 16; kt++) {
        const int kv0 = (pr * 16 + kt) * 64;
        __syncthreads();
        // stage K-tile: 64 rows x 128 cols (pair-private), 1024 chunks / 128 thr
        for (int j = 0; j < 8; j++) {
            int flat = j * 128 + pt;
            int row = flat >> 4, c16 = flat & 15;
            *(short8*)&Kl[pr][row][c16 * 8] = *(const short8*)(kp + (size_t)(kv0 + row) * 128 + c16 * 8);
        }
        // stage V-tile (pre-transposed): 128 rows(d) x 64 cols(kv)
        for (int j = 0; j < 8; j++) {
            int flat = j * 128 + pt;
            int row = flat >> 3, c8 = flat & 7;
            *(short8*)&Vl[pr][row][c8 * 8] = *(const short8*)(vp + (size_t)row * 2048 + kv0 + c8 * 8);
        }
        __syncthreads();

        // S = Q K^T  (16 q-rows x 64 kv per wave)
        floatx4 sa[4];
        for (int nt = 0; nt < 4; nt++) {
            sa[nt] = (floatx4)0.0f;
            for (int ks = 0; ks < 4; ks++) {
                short8 bfr = *(short8*)&Kl[pr][16 * nt + l16][ks * 32 + q4 * 8];
                sa[nt] = MFMA16(qf[ks], bfr, sa[nt]);
            }
        }

        // online softmax (rows = q4*4+r, cols = 16*nt+l16)
        float p[4][4], mnew[4], alpha[4];
        for (int r = 0; r < 4; r++) {
            float mx = fmaxf(fmaxf(sa[0][r], sa[1][r]), fmaxf(sa[2][r], sa[3][r]));
            mx *= SL;
            for (int off = 8; off >= 1; off >>= 1) mx = fmaxf(mx, __shfl_xor(mx, off, 64));
            mnew[r] = fmaxf(m_i[r], mx);
            alpha[r] = __builtin_amdgcn_exp2f(m_i[r] - mnew[r]);
            float rs = 0.f;
            for (int nt = 0; nt < 4; nt++) {
                float pv = __builtin_amdgcn_exp2f(sa[nt][r] * SL - mnew[r]);
                p[nt][r] = pv;
                rs += pv;
            }
            for (int off = 8; off >= 1; off >>= 1) rs += __shfl_xor(rs, off, 64);
            l_i[r] = l_i[r] * alpha[r] + rs;
            m_i[r] = mnew[r];
        }
        for (int dt = 0; dt < 8; dt++)
            for (int r = 0; r < 4; r++) oacc[dt][r] *= alpha[r];

        // P: C-layout -> LDS (wave-private rows; same-wave RAW waitcnt-ordered)
        for (int nt = 0; nt < 4; nt++)
            for (int r = 0; r < 4; r++)
                Pl[pr][16 * wq + q4 * 4 + r][16 * nt + l16] = f2bf(p[nt][r]);

        // O += P V
        short8 pf0 = *(short8*)&Pl[pr][16 * wq + l16][q4 * 8];
        short8 pf1 = *(short8*)&Pl[pr][16 * wq + l16][32 + q4 * 8];
        for (int dt = 0; dt < 8; dt++) {
            short8 v0 = *(short8*)&Vl[pr][16 * dt + l16][q4 * 8];
            short8 v1 = *(short8*)&Vl[pr][16 * dt + l16][32 + q4 * 8];
            oacc[dt] = MFMA16(pf0, v0, oacc[dt]);
            oacc[dt] = MFMA16(pf1, v1, oacc[dt]);
        }
    }

    // ---- merge the two kv-halves (LSE) ----
    __syncthreads();
    float* Om = (float*)&Kl[0][0][0];     // 32x128 f32 = 16KB (fits in Kl)
    float* Mm = (float*)&Vl[0][0][0];     // 32 floats
    float* Lm = Mm + 64;
    if (pr == 1) {
        for (int dt = 0; dt < 8; dt++)
            for (int r = 0; r < 4; r++)
                Om[(16 * wq + q4 * 4 + r) * 128 + 16 * dt + l16] = oacc[dt][r];
        if (l16 == 0)
            for (int r = 0; r < 4; r++) {
                Mm[16 * wq + q4 * 4 + r] = m_i[r];
                Lm[16 * wq + q4 * 4 + r] = l_i[r];
            }
    }
    __syncthreads();
    if (pr == 0) {
        float s0[4], s1[4];
        for (int r = 0; r < 4; r++) {
            int row = 16 * wq + q4 * 4 + r;
            float m1 = Mm[row], l1 = Lm[row];
            float M = fmaxf(m_i[r], m1);
            float a0 = __builtin_amdgcn_exp2f(m_i[r] - M);
            float a1 = __builtin_amdgcn_exp2f(m1 - M);
            float inv = 1.0f / (l_i[r] * a0 + l1 * a1);
            s0[r] = a0 * inv; s1[r] = a1 * inv;
        }
        for (int dt = 0; dt < 8; dt++) {
            for (int r = 0; r < 4; r++) {
                int row = 16 * wq + q4 * 4 + r;
                int qrow = bq * 32 + row;
                out[((size_t)b * 2048 + qrow) * 128 + 16 * dt + l16] =
                    oacc[dt][r] * s0[r] + Om[row * 128 + 16 * dt + l16] * s1[r];
            }
        }
    }
}

extern "C" void kernel_launch(void* const* d_in, const int* in_sizes, int n_in,
                              void* d_out, int out_size, void* d_ws, size_t ws_size,
                              hipStream_t stream) {
    const float* query = (const float*)d_in[0];
    const float* key   = (const float*)d_in[1];
    const float* value = (const float*)d_in[2];
    const float* Wq    = (const float*)d_in[3];
    const float* bq    = (const float*)d_in[4];
    const float* Wk    = (const float*)d_in[5];
    const float* bk    = (const float*)d_in[6];
    const float* Wv    = (const float*)d_in[7];
    const float* bv    = (const float*)d_in[8];
    float* out = (float*)d_out;

    // ws layout (shorts): Wt[3][128][1024] | q[16384][128] | k[16384][128] | vt[8][128][2048]
    short* wt  = (short*)d_ws;
    short* qws = wt + 3 * 131072;
    short* kws = qws + 16384 * 128;
    short* vws = kws + 16384 * 128;

    wconv_kernel<<<1536, 256, 0, stream>>>(Wq, Wk, Wv, wt);
    proj_kernel<<<dim3(256, 3), 256, 0, stream>>>(query, key, value, wt,
                                                  bq, bk, bv, qws, kws, vws);
    flash_kernel<<<dim3(64, 8), 256, 0, stream>>>(qws, kws, vws, out);
}